// Round 8
// baseline (64.037 us; speedup 1.0000x reference)
//
#include <hip/hip_runtime.h>

#define BATCH 256
#define ZCHUNK 8          // z-values per thread -> 8 accumulators; grid.y = 32

// Fused prep: segment bounds of the row-contiguous COO (scatter; no init pass —
// consumer validates against 0xAA poison) + global transpose f -> fT[c][z].
__global__ __launch_bounds__(256) void prep(
    const float* __restrict__ f, const int* __restrict__ rows,
    int* __restrict__ rstart, int* __restrict__ rend,
    float* __restrict__ fT, int nnz, int dim_in, int nF, int do_transpose)
{
    const int i = blockIdx.x * blockDim.x + threadIdx.x;
    if (i < nnz) {
        const int r = rows[i];
        if (i == 0 || rows[i - 1] != r) rstart[r] = i;
        if (i == nnz - 1 || rows[i + 1] != r) rend[r] = i + 1;
    }
    if (do_transpose && i < nF) {
        const int z = i / dim_in;            // coalesced read of f
        const int c = i - z * dim_in;
        fT[(size_t)c * BATCH + z] = f[i];
    }
}

// No LDS, no barriers: fT (426 KB) is L2-resident; stream entries from L2.
// One thread = one (output row, 8-z chunk). 8 coalesced stores, once each.
__global__ __launch_bounds__(256) void tsq_direct(
    const float* __restrict__ fT, const float* __restrict__ vals,
    const int* __restrict__ ci, const int* __restrict__ cj,
    const int* __restrict__ rstart, const int* __restrict__ rend,
    float* __restrict__ out, int dim_out, int nnz)
{
    const int r = blockIdx.x * blockDim.x + threadIdx.x;
    if (r >= dim_out) return;
    const int z0 = blockIdx.y * ZCHUNK;

    // bounds from scatter; untouched rows still hold 0xAA poison -> reject
    int s = 0, e1 = 0;
    {
        const int ss = rstart[r];
        const int ee = rend[r];
        if (ss >= 0 && ee > ss && ee <= nnz) { s = ss; e1 = ee; }
    }

    float4 a0 = {0, 0, 0, 0}, a1 = {0, 0, 0, 0};

    for (int e = s; e < e1; ++e) {
        const int   a = ci[e];
        const int   b = cj[e];
        const float v = vals[e];
        const float* __restrict__ pa = fT + (size_t)a * BATCH + z0;
        const float* __restrict__ pb = fT + (size_t)b * BATCH + z0;
        const float4 xa0 = *(const float4*)(pa);
        const float4 xb0 = *(const float4*)(pb);
        const float4 xa1 = *(const float4*)(pa + 4);
        const float4 xb1 = *(const float4*)(pb + 4);
        a0.x += v * xa0.x * xb0.x;  a0.y += v * xa0.y * xb0.y;
        a0.z += v * xa0.z * xb0.z;  a0.w += v * xa0.w * xb0.w;
        a1.x += v * xa1.x * xb1.x;  a1.y += v * xa1.y * xb1.y;
        a1.z += v * xa1.z * xb1.z;  a1.w += v * xa1.w * xb1.w;
    }

    // 8 coalesced nontemporal stores (wave = 64 consecutive r -> 256B/store)
    float* o = out + (size_t)z0 * dim_out + r;
    const size_t d = dim_out;
    __builtin_nontemporal_store(a0.x, o);        __builtin_nontemporal_store(a0.y, o + d);
    __builtin_nontemporal_store(a0.z, o + 2*d);  __builtin_nontemporal_store(a0.w, o + 3*d);
    __builtin_nontemporal_store(a1.x, o + 4*d);  __builtin_nontemporal_store(a1.y, o + 5*d);
    __builtin_nontemporal_store(a1.z, o + 6*d);  __builtin_nontemporal_store(a1.w, o + 7*d);
}

// Fallback (workspace too small for fT): read f rows directly, one z per block.y.
__global__ __launch_bounds__(256) void tsq_fallback(
    const float* __restrict__ f, const float* __restrict__ vals,
    const int* __restrict__ ci, const int* __restrict__ cj,
    const int* __restrict__ rstart, const int* __restrict__ rend,
    float* __restrict__ out, int dim_in, int dim_out, int nnz)
{
    const int r = blockIdx.x * blockDim.x + threadIdx.x;
    if (r >= dim_out) return;
    const int z = blockIdx.y;
    const float* __restrict__ fb = f + (size_t)z * dim_in;
    const int ss = rstart[r];
    const int ee = rend[r];
    float acc = 0.0f;
    if (ss >= 0 && ee > ss && ee <= nnz) {
        for (int e = ss; e < ee; ++e)
            acc += vals[e] * fb[ci[e]] * fb[cj[e]];
    }
    out[(size_t)z * dim_out + r] = acc;
}

extern "C" void kernel_launch(void* const* d_in, const int* in_sizes, int n_in,
                              void* d_out, int out_size, void* d_ws, size_t ws_size,
                              hipStream_t stream)
{
    const float* f    = (const float*)d_in[0];
    const float* vals = (const float*)d_in[1];
    const int*   rows = (const int*)d_in[2];
    const int*   ci   = (const int*)d_in[3];
    const int*   cj   = (const int*)d_in[4];
    float*       out  = (float*)d_out;

    const int nnz     = in_sizes[1];
    const int nF      = in_sizes[0];
    const int dim_in  = nF / BATCH;
    const int dim_out = out_size / BATCH;

    int*   rstart = (int*)d_ws;
    int*   rend   = rstart + dim_out;
    float* fT     = (float*)(rend + dim_out);

    const int use_main =
        (ws_size >= (size_t)(2 * dim_out) * sizeof(int) + (size_t)nF * sizeof(float));

    const int prep_n = nnz > nF ? nnz : nF;
    prep<<<(prep_n + 255) / 256, 256, 0, stream>>>(f, rows, rstart, rend, fT,
                                                   nnz, dim_in, nF, use_main);

    if (use_main) {
        dim3 grid((dim_out + 255) / 256, BATCH / ZCHUNK);
        tsq_direct<<<grid, 256, 0, stream>>>(fT, vals, ci, cj, rstart, rend,
                                             out, dim_out, nnz);
    } else {
        dim3 grid((dim_out + 255) / 256, BATCH);
        tsq_fallback<<<grid, 256, 0, stream>>>(f, vals, ci, cj, rstart, rend,
                                               out, dim_in, dim_out, nnz);
    }
}

// Round 9
// 36.435 us; speedup vs baseline: 1.7576x; 1.7576x over previous
//
#include <hip/hip_runtime.h>

#define BATCH 256
#define ZTILE 16          // z per LDS tile
#define NZT 4             // tiles per block -> 64 z per block; grid.y = 4
#define PADF 20           // floats per stripe (16 z + 4 pad) = 80 B; spreads bank starts
#define CAP 16            // register-cached entries per row
#define DIN_CAP 416       // dim_in for this problem

// Fused prep: segment bounds of the row-contiguous COO (scatter; no init pass —
// consumer validates against 0xAA poison) + global transpose f -> fT[c][z].
__global__ __launch_bounds__(256) void prep(
    const float* __restrict__ f, const int* __restrict__ rows,
    int* __restrict__ rstart, int* __restrict__ rend,
    float* __restrict__ fT, int nnz, int dim_in, int nF, int do_transpose)
{
    const int i = blockIdx.x * blockDim.x + threadIdx.x;
    if (i < nnz) {
        const int r = rows[i];
        if (i == 0 || rows[i - 1] != r) rstart[r] = i;
        if (i == nnz - 1 || rows[i + 1] != r) rend[r] = i + 1;
    }
    if (do_transpose && i < nF) {
        const int z = i / dim_in;            // coalesced read of f
        const int c = i - z * dim_in;
        fT[(size_t)c * BATCH + z] = f[i];
    }
}

// LDS-sync without store drain: barrier needs only lgkmcnt(0), NOT vmcnt(0).
// __syncthreads() would force s_waitcnt vmcnt(0) -> previous tile's 16 HBM
// stores must drain before restaging. Raw s_barrier + manual lgkm wait lets
// stores stay in flight across tiles.
__device__ __forceinline__ void lds_sync()
{
    asm volatile("s_waitcnt lgkmcnt(0)" ::: "memory");
    __builtin_amdgcn_sched_barrier(0);
    __builtin_amdgcn_s_barrier();
    __builtin_amdgcn_sched_barrier(0);
}

__global__ __launch_bounds__(256) void tsq_main(
    const float* __restrict__ fT, const float* __restrict__ vals,
    const int* __restrict__ ci, const int* __restrict__ cj,
    const int* __restrict__ rstart, const int* __restrict__ rend,
    float* __restrict__ out, int dim_in, int dim_out, int nnz)
{
    __shared__ __align__(16) float fzT[DIN_CAP * PADF];   // 33280 B -> 4 blocks/CU

    const int r = blockIdx.x * blockDim.x + threadIdx.x;
    const bool valid = (r < dim_out);

    // bounds from scatter; untouched rows still hold 0xAA poison -> reject
    int s = 0, e1 = 0;
    if (valid) {
        const int ss = rstart[r];
        const int ee = rend[r];
        if (ss >= 0 && ee >= ss && ee <= nnz) { s = ss; e1 = ee; }
    }
    const int cnt  = e1 - s;
    const int creg = cnt < CAP ? cnt : CAP;

    // entries -> registers once per block (static-indexed, predicated, early-exit)
    int pa_[CAP]; int pb_[CAP]; float ev_[CAP];
#pragma unroll
    for (int i = 0; i < CAP; ++i) {
        if (!__any(i < creg)) break;
        if (i < creg) {
            pa_[i] = ci[s + i] * (PADF * 4);   // stripe byte offset
            pb_[i] = cj[s + i] * (PADF * 4);
            ev_[i] = vals[s + i];
        }
    }

    const int zbase = blockIdx.y * (ZTILE * NZT);
    const int nchunk = dim_in * (ZTILE / 4);   // float4 chunks per stage

    for (int t = 0; t < NZT; ++t) {
        const int z0 = zbase + t * ZTILE;

        // ---- stage fzT[c][0..15] = fT[c][z0..z0+15]; float4 both sides
        for (int i = threadIdx.x; i < nchunk; i += blockDim.x) {
            const int c  = i >> 2;
            const int zq = i & 3;
            const float4 v = *(const float4*)(fT + (size_t)c * BATCH + z0 + zq * 4);
            *(float4*)(fzT + c * PADF + zq * 4) = v;
        }
        lds_sync();   // ds_writes visible; previous tile's stores NOT drained

        float4 a0 = {0,0,0,0}, a1 = {0,0,0,0}, a2 = {0,0,0,0}, a3 = {0,0,0,0};
#pragma unroll
        for (int i = 0; i < CAP; ++i) {
            if (!__any(i < creg)) break;       // wave-uniform early exit
            if (i < creg) {
                const float v = ev_[i];
                const char* ba = (const char*)fzT + pa_[i];
                const char* bb = (const char*)fzT + pb_[i];
                float4 xa, xb;
                xa = *(const float4*)(ba);      xb = *(const float4*)(bb);
                a0.x += v*xa.x*xb.x; a0.y += v*xa.y*xb.y; a0.z += v*xa.z*xb.z; a0.w += v*xa.w*xb.w;
                xa = *(const float4*)(ba + 16); xb = *(const float4*)(bb + 16);
                a1.x += v*xa.x*xb.x; a1.y += v*xa.y*xb.y; a1.z += v*xa.z*xb.z; a1.w += v*xa.w*xb.w;
                xa = *(const float4*)(ba + 32); xb = *(const float4*)(bb + 32);
                a2.x += v*xa.x*xb.x; a2.y += v*xa.y*xb.y; a2.z += v*xa.z*xb.z; a2.w += v*xa.w*xb.w;
                xa = *(const float4*)(ba + 48); xb = *(const float4*)(bb + 48);
                a3.x += v*xa.x*xb.x; a3.y += v*xa.y*xb.y; a3.z += v*xa.z*xb.z; a3.w += v*xa.w*xb.w;
            }
        }
        for (int e = s + CAP; e < e1; ++e) {   // rare long rows
            const int a = ci[e], b = cj[e]; const float v = vals[e];
            const float* ba = fzT + a * PADF;
            const float* bb = fzT + b * PADF;
#pragma unroll
            for (int q = 0; q < 4; ++q) {
                const float4 xa = *(const float4*)(ba + q * 4);
                const float4 xb = *(const float4*)(bb + q * 4);
                float4* ac = q == 0 ? &a0 : q == 1 ? &a1 : q == 2 ? &a2 : &a3;
                ac->x += v*xa.x*xb.x; ac->y += v*xa.y*xb.y;
                ac->z += v*xa.z*xb.z; ac->w += v*xa.w*xb.w;
            }
        }

        if (valid) {   // 16 coalesced nontemporal stores; left in flight
            float* o = out + (size_t)z0 * dim_out + r;
            const size_t d = dim_out;
            __builtin_nontemporal_store(a0.x, o);          __builtin_nontemporal_store(a0.y, o + d);
            __builtin_nontemporal_store(a0.z, o + 2*d);    __builtin_nontemporal_store(a0.w, o + 3*d);
            __builtin_nontemporal_store(a1.x, o + 4*d);    __builtin_nontemporal_store(a1.y, o + 5*d);
            __builtin_nontemporal_store(a1.z, o + 6*d);    __builtin_nontemporal_store(a1.w, o + 7*d);
            __builtin_nontemporal_store(a2.x, o + 8*d);    __builtin_nontemporal_store(a2.y, o + 9*d);
            __builtin_nontemporal_store(a2.z, o + 10*d);   __builtin_nontemporal_store(a2.w, o + 11*d);
            __builtin_nontemporal_store(a3.x, o + 12*d);   __builtin_nontemporal_store(a3.y, o + 13*d);
            __builtin_nontemporal_store(a3.z, o + 14*d);   __builtin_nontemporal_store(a3.w, o + 15*d);
        }
        lds_sync();   // all waves' ds_reads done -> safe to restage next tile
    }
}

// Fallback for dim_in > DIN_CAP: reads f directly, one z per block.y.
__global__ __launch_bounds__(256) void tsq_fallback(
    const float* __restrict__ f, const float* __restrict__ vals,
    const int* __restrict__ ci, const int* __restrict__ cj,
    const int* __restrict__ rstart, const int* __restrict__ rend,
    float* __restrict__ out, int dim_in, int dim_out, int nnz)
{
    const int r = blockIdx.x * blockDim.x + threadIdx.x;
    if (r >= dim_out) return;
    const int z = blockIdx.y;
    const float* __restrict__ fb = f + (size_t)z * dim_in;
    const int ss = rstart[r];
    const int ee = rend[r];
    float acc = 0.0f;
    if (ss >= 0 && ee > ss && ee <= nnz) {
        for (int e = ss; e < ee; ++e)
            acc += vals[e] * fb[ci[e]] * fb[cj[e]];
    }
    out[(size_t)z * dim_out + r] = acc;
}

extern "C" void kernel_launch(void* const* d_in, const int* in_sizes, int n_in,
                              void* d_out, int out_size, void* d_ws, size_t ws_size,
                              hipStream_t stream)
{
    const float* f    = (const float*)d_in[0];
    const float* vals = (const float*)d_in[1];
    const int*   rows = (const int*)d_in[2];
    const int*   ci   = (const int*)d_in[3];
    const int*   cj   = (const int*)d_in[4];
    float*       out  = (float*)d_out;

    const int nnz     = in_sizes[1];
    const int nF      = in_sizes[0];
    const int dim_in  = nF / BATCH;
    const int dim_out = out_size / BATCH;

    int*   rstart = (int*)d_ws;
    int*   rend   = rstart + dim_out;
    float* fT     = (float*)(rend + dim_out);

    const int use_main = (dim_in <= DIN_CAP) &&
                         (ws_size >= (size_t)(2 * dim_out) * 4 + (size_t)nF * 4);

    const int prep_n = nnz > nF ? nnz : nF;
    prep<<<(prep_n + 255) / 256, 256, 0, stream>>>(f, rows, rstart, rend, fT,
                                                   nnz, dim_in, nF, use_main);

    if (use_main) {
        dim3 grid((dim_out + 255) / 256, BATCH / (ZTILE * NZT));
        tsq_main<<<grid, 256, 0, stream>>>(fT, vals, ci, cj, rstart, rend, out,
                                           dim_in, dim_out, nnz);
    } else {
        dim3 grid((dim_out + 255) / 256, BATCH);
        tsq_fallback<<<grid, 256, 0, stream>>>(f, vals, ci, cj, rstart, rend,
                                               out, dim_in, dim_out, nnz);
    }
}

// Round 10
// 35.790 us; speedup vs baseline: 1.7892x; 1.0180x over previous
//
#include <hip/hip_runtime.h>

#define BATCH 256
#define ZTILE 16          // z per LDS tile
#define NZT 2             // tiles per block -> 32 z per block; grid.y = 8
#define PADF 20           // floats per stripe (16 z + 4 pad) = 80 B; spreads bank starts
#define DIN_CAP 416       // dim_in for this problem

// ---------------- prep: tiled transpose f->fT + COO segment-bounds scatter ----
// blocks [0, TB): 32x32 transpose tiles via LDS (coalesced read AND write;
//                 each fT cache line written by exactly one block).
// blocks [TB, TB+NB): bounds scatter (no init pass; consumer rejects poison).
__global__ __launch_bounds__(256) void prep_t(
    const float* __restrict__ f, const int* __restrict__ rows,
    int* __restrict__ rstart, int* __restrict__ rend,
    float* __restrict__ fT, int nnz, int dim_in, int TB, int ctiles)
{
    const int bx = blockIdx.x;
    if (bx < TB) {
        __shared__ float lt[32][33];
        const int c0 = (bx % ctiles) * 32;
        const int z0 = (bx / ctiles) * 32;
        const int ic = threadIdx.x & 31;
        const int i0 = threadIdx.x >> 5;          // 0..7
#pragma unroll
        for (int k = 0; k < 4; ++k) {             // lt[a][b] = f[z0+a][c0+b]
            const int a = i0 + 8 * k;
            const int c = c0 + ic;
            lt[a][ic] = (c < dim_in) ? f[(size_t)(z0 + a) * dim_in + c] : 0.0f;
        }
        __syncthreads();
#pragma unroll
        for (int k = 0; k < 4; ++k) {             // fT[c0+b][z0+a], lane->z
            const int b = i0 + 8 * k;
            const int c = c0 + b;
            if (c < dim_in)
                fT[(size_t)c * BATCH + z0 + ic] = lt[ic][b];
        }
    } else {
        const int e = (bx - TB) * 256 + threadIdx.x;
        if (e < nnz) {
            const int r = rows[e];
            if (e == 0 || rows[e - 1] != r) rstart[r] = e;
            if (e == nnz - 1 || rows[e + 1] != r) rend[r] = e + 1;
        }
    }
}

// Barrier that waits only on LDS ops (lgkmcnt), leaving HBM stores in flight.
__device__ __forceinline__ void lds_sync()
{
    asm volatile("s_waitcnt lgkmcnt(0)" ::: "memory");
    __builtin_amdgcn_sched_barrier(0);
    __builtin_amdgcn_s_barrier();
    __builtin_amdgcn_sched_barrier(0);
}

__global__ __launch_bounds__(256) void tsq_main(
    const float* __restrict__ fT, const float* __restrict__ vals,
    const int* __restrict__ ci, const int* __restrict__ cj,
    const int* __restrict__ rstart, const int* __restrict__ rend,
    float* __restrict__ out, int dim_in, int dim_out, int nnz)
{
    __shared__ __align__(16) float fzT[DIN_CAP * PADF];   // 33280 B -> 4 blocks/CU

    const int r = blockIdx.x * blockDim.x + threadIdx.x;
    const bool valid = (r < dim_out);

    // bounds from scatter; untouched rows still hold 0xAA poison -> reject
    int s = 0, e1 = 0;
    if (valid) {
        const int ss = rstart[r];
        const int ee = rend[r];
        if (ss >= 0 && ee > ss && ee <= nnz) { s = ss; e1 = ee; }
    }

    const int zbase = blockIdx.y * (ZTILE * NZT);
    const int nchunk = dim_in * (ZTILE / 4);   // float4 chunks per stage

    for (int t = 0; t < NZT; ++t) {
        const int z0 = zbase + t * ZTILE;

        // stage fzT[c][0..15] = fT[c][z0..z0+15]; float4 both sides
        for (int i = threadIdx.x; i < nchunk; i += blockDim.x) {
            const int c  = i >> 2;
            const int zq = i & 3;
            const float4 v = *(const float4*)(fT + (size_t)c * BATCH + z0 + zq * 4);
            *(float4*)(fzT + c * PADF + zq * 4) = v;
        }
        lds_sync();   // ds_writes visible; stores from previous tile stay in flight

        float4 a0 = {0,0,0,0}, a1 = {0,0,0,0}, a2 = {0,0,0,0}, a3 = {0,0,0,0};
        for (int e = s; e < e1; ++e) {         // avg ~2 entries; indices from L2
            const int   a = ci[e];
            const int   b = cj[e];
            const float v = vals[e];
            const float* ba = fzT + a * PADF;
            const float* bb = fzT + b * PADF;
            float4 xa, xb;
            xa = *(const float4*)(ba);      xb = *(const float4*)(bb);
            a0.x += v*xa.x*xb.x; a0.y += v*xa.y*xb.y; a0.z += v*xa.z*xb.z; a0.w += v*xa.w*xb.w;
            xa = *(const float4*)(ba + 4);  xb = *(const float4*)(bb + 4);
            a1.x += v*xa.x*xb.x; a1.y += v*xa.y*xb.y; a1.z += v*xa.z*xb.z; a1.w += v*xa.w*xb.w;
            xa = *(const float4*)(ba + 8);  xb = *(const float4*)(bb + 8);
            a2.x += v*xa.x*xb.x; a2.y += v*xa.y*xb.y; a2.z += v*xa.z*xb.z; a2.w += v*xa.w*xb.w;
            xa = *(const float4*)(ba + 12); xb = *(const float4*)(bb + 12);
            a3.x += v*xa.x*xb.x; a3.y += v*xa.y*xb.y; a3.z += v*xa.z*xb.z; a3.w += v*xa.w*xb.w;
        }

        if (valid) {   // 16 coalesced nontemporal stores; left in flight
            float* o = out + (size_t)z0 * dim_out + r;
            const size_t d = dim_out;
            __builtin_nontemporal_store(a0.x, o);          __builtin_nontemporal_store(a0.y, o + d);
            __builtin_nontemporal_store(a0.z, o + 2*d);    __builtin_nontemporal_store(a0.w, o + 3*d);
            __builtin_nontemporal_store(a1.x, o + 4*d);    __builtin_nontemporal_store(a1.y, o + 5*d);
            __builtin_nontemporal_store(a1.z, o + 6*d);    __builtin_nontemporal_store(a1.w, o + 7*d);
            __builtin_nontemporal_store(a2.x, o + 8*d);    __builtin_nontemporal_store(a2.y, o + 9*d);
            __builtin_nontemporal_store(a2.z, o + 10*d);   __builtin_nontemporal_store(a2.w, o + 11*d);
            __builtin_nontemporal_store(a3.x, o + 12*d);   __builtin_nontemporal_store(a3.y, o + 13*d);
            __builtin_nontemporal_store(a3.z, o + 14*d);   __builtin_nontemporal_store(a3.w, o + 15*d);
        }
        lds_sync();   // all waves' ds_reads done -> safe to restage
    }
}

// Fallback for dim_in > DIN_CAP or tiny workspace: reads f directly.
__global__ __launch_bounds__(256) void tsq_fallback(
    const float* __restrict__ f, const float* __restrict__ vals,
    const int* __restrict__ ci, const int* __restrict__ cj,
    const int* __restrict__ rstart, const int* __restrict__ rend,
    float* __restrict__ out, int dim_in, int dim_out, int nnz)
{
    const int r = blockIdx.x * blockDim.x + threadIdx.x;
    if (r >= dim_out) return;
    const int z = blockIdx.y;
    const float* __restrict__ fb = f + (size_t)z * dim_in;
    const int ss = rstart[r];
    const int ee = rend[r];
    float acc = 0.0f;
    if (ss >= 0 && ee > ss && ee <= nnz) {
        for (int e = ss; e < ee; ++e)
            acc += vals[e] * fb[ci[e]] * fb[cj[e]];
    }
    out[(size_t)z * dim_out + r] = acc;
}

extern "C" void kernel_launch(void* const* d_in, const int* in_sizes, int n_in,
                              void* d_out, int out_size, void* d_ws, size_t ws_size,
                              hipStream_t stream)
{
    const float* f    = (const float*)d_in[0];
    const float* vals = (const float*)d_in[1];
    const int*   rows = (const int*)d_in[2];
    const int*   ci   = (const int*)d_in[3];
    const int*   cj   = (const int*)d_in[4];
    float*       out  = (float*)d_out;

    const int nnz     = in_sizes[1];
    const int nF      = in_sizes[0];
    const int dim_in  = nF / BATCH;
    const int dim_out = out_size / BATCH;

    int*   rstart = (int*)d_ws;
    int*   rend   = rstart + dim_out;
    float* fT     = (float*)(rend + dim_out);

    const int use_main = (dim_in <= DIN_CAP) &&
                         (ws_size >= (size_t)(2 * dim_out) * 4 + (size_t)nF * 4);

    const int ctiles = (dim_in + 31) / 32;
    const int TB = use_main ? ctiles * (BATCH / 32) : 0;   // transpose tile blocks
    const int NB = (nnz + 255) / 256;                      // bounds blocks
    prep_t<<<TB + NB, 256, 0, stream>>>(f, rows, rstart, rend, fT,
                                        nnz, dim_in, TB, ctiles);

    if (use_main) {
        dim3 grid((dim_out + 255) / 256, BATCH / (ZTILE * NZT));
        tsq_main<<<grid, 256, 0, stream>>>(fT, vals, ci, cj, rstart, rend, out,
                                           dim_in, dim_out, nnz);
    } else {
        dim3 grid((dim_out + 255) / 256, BATCH);
        tsq_fallback<<<grid, 256, 0, stream>>>(f, vals, ci, cj, rstart, rend,
                                               out, dim_in, dim_out, nnz);
    }
}